// Round 7
// baseline (101.789 us; speedup 1.0000x reference)
//
#include <hip/hip_runtime.h>

// Problem constants (match reference)
#define GS    20
#define PARAM 40
#define NSYS  80             // B * A = 8 * 10
#define NLOC  (GS * PARAM)   // 800 unknowns per system
#define NTH   400
#define INNER 5              // Jacobi sweeps for G=S^-1 Ng, c=S^-1 v (||B||~0.33); odd
#define OUTER 3              // block-preconditioned sweeps (rho ~ 0.15)

// Solve (I (x) S + M (x) Ng) x = v, then clip to [-1,1].
// Block form, row i:  x_i = S^-1 v_i - (S^-1 Ng) sum_j M[i,j] x_j  =  c_i - G z_i
// Setup (inner): G and c via point-Jacobi on S (S' rows in VGPRs, G column-major in LDS;
//                last sweep also mirrors G row-major so outer register loads are b128).
// Outer: phase1 Z = M X (float4), phase2 x' = c - G Z (G rows in VGPRs).
// NOTE (R6 lesson): ALL global reads must stay coalesced float4 — per-thread scalar
// global reads at stride 160B exploded FETCH_SIZE 2.4->11.8 MB and tripled dispatch time.
__global__ __launch_bounds__(NTH) void gliam_solve(
    const float* __restrict__ mat,   // (NSYS, GS, GS)
    const float* __restrict__ val,   // (NSYS, GS, PARAM)
    const float* __restrict__ S,     // (PARAM, PARAM)
    const float* __restrict__ Ng,    // (PARAM, PARAM)
    float* __restrict__ out)         // (NSYS, GS, PARAM)
{
    __shared__ float4 sSoff[PARAM * 11];    // D^-1 S, diag zeroed, rows padded to 44 floats
    __shared__ float4 sNgP [PARAM * 11];    // raw Ng, padded (staged coalesced)
    __shared__ float  sRD  [PARAM];         // 1 / S[p][p]
    __shared__ float  sM   [GS * GS];
    __shared__ float4 sGc  [2][PARAM * 11]; // G iterate, column-major: col u at [u*11..]
    __shared__ float4 sGrm [PARAM * 11];    // final G, row-major (padded 44)
    __shared__ float4 sXv  [2][NLOC / 4];   // state X (also c-iteration buffer)
    __shared__ float4 sZ   [NLOC / 4];      // Z = M·X

    const int sys = blockIdx.x;
    const int t   = threadIdx.x;
    const int pb  = t % 10;   // float4 row-block: rows 4pb..4pb+3
    const int u   = t / 10;   // 0..39: G column index; (u<20) also c system-row

    // ---- stage (coalesced float4) + fold D^-1 into S rows ----
    {
        const float rd = 1.0f / S[u * PARAM + u];    // 40 distinct addrs, L1 broadcast
        float4 a = ((const float4*)S)[t];            // row u, float4 block pb (coalesced)
        a.x *= rd; a.y *= rd; a.z *= rd; a.w *= rd;
        if (pb == (u >> 2)) ((float*)&a)[u & 3] = 0.0f;   // zero diagonal entry
        sSoff[u * 11 + pb] = a;
        sNgP [u * 11 + pb] = ((const float4*)Ng)[t]; // coalesced
    }
    if (t < PARAM) sRD[t] = 1.0f / S[t * PARAM + t];
    sM[t] = mat[sys * GS * GS + t];                  // GS*GS == NTH == 400, coalesced
    __syncthreads();

    // ---- per-thread registers: S' rows 4pb..4pb+3; ngd / vd for column u ----
    float4 sr0[10], sr1[10], sr2[10], sr3[10];
    float4 ngd, vd = make_float4(0.f, 0.f, 0.f, 0.f);
    {
        #pragma unroll
        for (int k = 0; k < 10; ++k) {
            sr0[k] = sSoff[(4*pb+0)*11 + k];
            sr1[k] = sSoff[(4*pb+1)*11 + k];
            sr2[k] = sSoff[(4*pb+2)*11 + k];
            sr3[k] = sSoff[(4*pb+3)*11 + k];
        }
        const float* Ngf = (const float*)sNgP;       // LDS transpose-gather (once)
        const float rd0 = sRD[4*pb+0], rd1 = sRD[4*pb+1],
                    rd2 = sRD[4*pb+2], rd3 = sRD[4*pb+3];
        ngd.x = Ngf[(4*pb+0)*44 + u] * rd0;
        ngd.y = Ngf[(4*pb+1)*44 + u] * rd1;
        ngd.z = Ngf[(4*pb+2)*44 + u] * rd2;
        ngd.w = Ngf[(4*pb+3)*44 + u] * rd3;
        sGc[0][u*11 + pb] = ngd;                     // G0 = D^-1 Ng (column-major)
        if (u < GS) {
            const float4 v4 = *(const float4*)&val[sys*NLOC + u*PARAM + 4*pb]; // coalesced
            vd.x = v4.x * rd0; vd.y = v4.y * rd1; vd.z = v4.z * rd2; vd.w = v4.w * rd3;
            sXv[0][u*10 + pb] = vd;                  // c0 = D^-1 v
        }
    }
    __syncthreads();

    // ---- inner sweeps: G <- Ngd - S'off G ;  c <- Vd - S'off c ----
    #pragma unroll
    for (int s = 0; s < INNER; ++s) {
        const int cur = s & 1, nxt = cur ^ 1;
        float4 accG = ngd;
        float4 accC = vd;
        const float4* gcol = &sGc[cur][u * 11];
        #pragma unroll
        for (int k = 0; k < 10; ++k) {
            const float4 g = gcol[k];
            accG.x -= sr0[k].x*g.x + sr0[k].y*g.y + sr0[k].z*g.z + sr0[k].w*g.w;
            accG.y -= sr1[k].x*g.x + sr1[k].y*g.y + sr1[k].z*g.z + sr1[k].w*g.w;
            accG.z -= sr2[k].x*g.x + sr2[k].y*g.y + sr2[k].z*g.z + sr2[k].w*g.w;
            accG.w -= sr3[k].x*g.x + sr3[k].y*g.y + sr3[k].z*g.z + sr3[k].w*g.w;
        }
        if (u < GS) {
            const float4* ccol = &sXv[cur][u * 10];
            #pragma unroll
            for (int k = 0; k < 10; ++k) {
                const float4 c = ccol[k];
                accC.x -= sr0[k].x*c.x + sr0[k].y*c.y + sr0[k].z*c.z + sr0[k].w*c.w;
                accC.y -= sr1[k].x*c.x + sr1[k].y*c.y + sr1[k].z*c.z + sr1[k].w*c.w;
                accC.z -= sr2[k].x*c.x + sr2[k].y*c.y + sr2[k].z*c.z + sr2[k].w*c.w;
                accC.w -= sr3[k].x*c.x + sr3[k].y*c.y + sr3[k].z*c.z + sr3[k].w*c.w;
            }
            sXv[nxt][u*10 + pb] = accC;
        }
        if (s == INNER - 1) {
            // final sweep: mirror G row-major so outer register loads are ds_read_b128
            float* Grm = (float*)sGrm;                // G[r][q] at [r*44 + q]
            Grm[(4*pb+0)*44 + u] = accG.x;
            Grm[(4*pb+1)*44 + u] = accG.y;
            Grm[(4*pb+2)*44 + u] = accG.z;
            Grm[(4*pb+3)*44 + u] = accG.w;
        } else {
            sGc[nxt][u*11 + pb] = accG;
        }
        __syncthreads();
    }
    const int fin = INNER & 1;   // final c buffer index (1 for odd INNER)

    // ---- outer-loop registers: G rows p, p+20 (b128); c values; M row ----
    const int i = t / GS;        // block-row 0..19
    const int p = t % GS;        // component 0..19; partner p+20
    float4 gr0[10], gr1[10];
    #pragma unroll
    for (int k = 0; k < 10; ++k) {
        gr0[k] = sGrm[p * 11 + k];
        gr1[k] = sGrm[(p + 20) * 11 + k];
    }
    const float c0 = ((const float*)sXv[fin])[i*PARAM + p];
    const float c1 = ((const float*)sXv[fin])[i*PARAM + p + 20];
    float mrow[GS];
    if (t < 200) {
        const int zi = t / 10;
        #pragma unroll
        for (int j = 0; j < GS; ++j) mrow[j] = sM[zi*GS + j];
    }
    // (reads only — all data final behind the last inner barrier; x0 = c in sXv[fin])

    int cur = fin;
    #pragma unroll
    for (int it = 0; it < OUTER; ++it) {
        // phase 1: Z[zi][cc4] = sum_j M[zi,j] * X[j][cc4]
        if (t < 200) {
            const int zi = t / 10, cc = t - (t/10)*10;
            const float4* X4 = sXv[cur];
            float4 acc = make_float4(0.f, 0.f, 0.f, 0.f);
            #pragma unroll
            for (int j = 0; j < GS; ++j) {
                const float  m = mrow[j];
                const float4 x = X4[j*10 + cc];
                acc.x += m*x.x; acc.y += m*x.y; acc.z += m*x.z; acc.w += m*x.w;
            }
            sZ[t] = acc;
        }
        __syncthreads();
        // phase 2: x'_{i,p} = c - Grow_p · Z_i  (two outputs share Z_i reads)
        const float4* Z4 = &sZ[i*10];
        float a0 = 0.f, a1 = 0.f;
        #pragma unroll
        for (int k = 0; k < 10; ++k) {
            const float4 z = Z4[k];
            a0 += gr0[k].x*z.x + gr0[k].y*z.y + gr0[k].z*z.z + gr0[k].w*z.w;
            a1 += gr1[k].x*z.x + gr1[k].y*z.y + gr1[k].z*z.z + gr1[k].w*z.w;
        }
        const float x0n = c0 - a0, x1n = c1 - a1;
        if (it == OUTER - 1) {
            // epilogue: advrelu(lo=-1,hi=1) == clip
            out[sys*NLOC + i*PARAM + p   ] = fminf(fmaxf(x0n, -1.f), 1.f);
            out[sys*NLOC + i*PARAM + p+20] = fminf(fmaxf(x1n, -1.f), 1.f);
        } else {
            ((float*)sXv[cur ^ 1])[i*PARAM + p   ] = x0n;
            ((float*)sXv[cur ^ 1])[i*PARAM + p+20] = x1n;
            __syncthreads();
            cur ^= 1;
        }
    }
}

extern "C" void kernel_launch(void* const* d_in, const int* in_sizes, int n_in,
                              void* d_out, int out_size, void* d_ws, size_t ws_size,
                              hipStream_t stream) {
    const float* mat = (const float*)d_in[0];  // 8*10*20*20 = 32000
    const float* val = (const float*)d_in[1];  // 8*10*20*40 = 64000
    const float* S   = (const float*)d_in[2];  // 40*40
    const float* Ng  = (const float*)d_in[3];  // 40*40
    float* out = (float*)d_out;                // 64000 f32

    gliam_solve<<<NSYS, NTH, 0, stream>>>(mat, val, S, Ng, out);
}

// Round 8
// 68.386 us; speedup vs baseline: 1.4885x; 1.4885x over previous
//
#include <hip/hip_runtime.h>

// Problem constants (match reference)
#define GS    20
#define PARAM 40
#define NSYS  80             // B * A = 8 * 10
#define NLOC  (GS * PARAM)   // 800 unknowns per system
#define NTH   400
#define INNER 5              // Jacobi sweeps for G=S^-1 Ng, c=S^-1 v (||B||~0.33); MUST be odd
#define OUTER 3              // block-preconditioned sweeps (rho ~ 0.15); R6/R7: absmax unchanged

// Solve (I (x) S + M (x) Ng) x = v, then clip to [-1,1].
// Block form, row i:  x_i = S^-1 v_i - (S^-1 Ng) sum_j M[i,j] x_j  =  c_i - G z_i
// Setup (inner): G and c via point-Jacobi on S (S' rows in VGPRs, G column-major in LDS).
// Outer: phase1 Z = M X (float4), phase2 x' = c - G Z (G rows in VGPRs).
//
// LESSONS (do not regress):
//  - R6: per-thread scalar global reads (stride 160B) are uncoalesced — keep ALL global
//    access as lane-contiguous float4.
//  - R6/R7: `#pragma unroll` on the INNER/OUTER sweep loops explodes live registers
//    (sr0-3 = 160 floats vs 128 VGPR cap) -> scratch spills -> FETCH 2.4->11.8 MB,
//    WRITE 0.25->22.5 MB, dispatch 14->48 us. Keep sweep loops ROLLED; the allocator
//    then rematerializes S' rows from LDS instead of spilling to scratch.
__global__ __launch_bounds__(NTH) void gliam_solve(
    const float* __restrict__ mat,   // (NSYS, GS, GS)
    const float* __restrict__ val,   // (NSYS, GS, PARAM)
    const float* __restrict__ S,     // (PARAM, PARAM)
    const float* __restrict__ Ng,    // (PARAM, PARAM)
    float* __restrict__ out)         // (NSYS, GS, PARAM)
{
    __shared__ float4 sSoff[PARAM * 11];   // D^-1 S, diag zeroed, rows padded to 44 floats
    __shared__ float4 sNgP [PARAM * 11];   // raw Ng, padded
    __shared__ float  sRD  [PARAM];        // 1 / S[p][p]
    __shared__ float  sM   [GS * GS];
    __shared__ float4 sGc  [2][PARAM * 11]; // G column-major: col u at [u*11 .. u*11+9]
    __shared__ float4 sXv  [2][NLOC / 4];   // state X (also c-iteration buffer)
    __shared__ float4 sZ   [NLOC / 4];      // Z = M·X

    const int sys = blockIdx.x;
    const int t   = threadIdx.x;
    const int pb  = t % 10;   // float4 row-block: rows 4pb..4pb+3
    const int u   = t / 10;   // 0..39: G column index; (u<20) also c system-row

    // ---- stage (coalesced float4) + fold D^-1 into S rows ----
    {
        const float rd = 1.0f / S[u * PARAM + u];    // 40 distinct addrs, L1 broadcast
        float4 a = ((const float4*)S)[t];            // row u, float4 block pb (coalesced)
        a.x *= rd; a.y *= rd; a.z *= rd; a.w *= rd;
        if (pb == (u >> 2)) ((float*)&a)[u & 3] = 0.0f;   // zero diagonal entry
        sSoff[u * 11 + pb] = a;
        sNgP [u * 11 + pb] = ((const float4*)Ng)[t]; // coalesced
    }
    if (t < PARAM) sRD[t] = 1.0f / S[t * PARAM + t];
    sM[t] = mat[sys * GS * GS + t];                  // GS*GS == NTH == 400, coalesced
    __syncthreads();

    // ---- per-thread registers: S' rows 4pb..4pb+3; Ngd/Vd constants for column u ----
    float4 sr0[10], sr1[10], sr2[10], sr3[10];
    float4 ngd, vd = make_float4(0.f, 0.f, 0.f, 0.f);
    {
        #pragma unroll
        for (int k = 0; k < 10; ++k) {
            sr0[k] = sSoff[(4*pb+0)*11 + k];
            sr1[k] = sSoff[(4*pb+1)*11 + k];
            sr2[k] = sSoff[(4*pb+2)*11 + k];
            sr3[k] = sSoff[(4*pb+3)*11 + k];
        }
        const float* Ngf = (const float*)sNgP;       // LDS transpose-gather (once)
        const float rd0 = sRD[4*pb+0], rd1 = sRD[4*pb+1],
                    rd2 = sRD[4*pb+2], rd3 = sRD[4*pb+3];
        ngd.x = Ngf[(4*pb+0)*44 + u] * rd0;
        ngd.y = Ngf[(4*pb+1)*44 + u] * rd1;
        ngd.z = Ngf[(4*pb+2)*44 + u] * rd2;
        ngd.w = Ngf[(4*pb+3)*44 + u] * rd3;
        sGc[0][u*11 + pb] = ngd;                     // G0 = D^-1 Ng (column-major)
        if (u < GS) {
            const float4 v4 = *(const float4*)&val[sys*NLOC + u*PARAM + 4*pb]; // coalesced
            vd.x = v4.x * rd0; vd.y = v4.y * rd1; vd.z = v4.z * rd2; vd.w = v4.w * rd3;
            sXv[0][u*10 + pb] = vd;                  // c0 = D^-1 v
        }
    }
    __syncthreads();

    // ---- inner sweeps (ROLLED): G <- Ngd - S'off G ;  c <- Vd - S'off c ----
    for (int s = 0; s < INNER; ++s) {
        const int cur = s & 1, nxt = cur ^ 1;
        float4 accG = ngd;
        float4 accC = vd;
        const float4* gcol = &sGc[cur][u * 11];
        #pragma unroll
        for (int k = 0; k < 10; ++k) {
            const float4 g = gcol[k];
            accG.x -= sr0[k].x*g.x + sr0[k].y*g.y + sr0[k].z*g.z + sr0[k].w*g.w;
            accG.y -= sr1[k].x*g.x + sr1[k].y*g.y + sr1[k].z*g.z + sr1[k].w*g.w;
            accG.z -= sr2[k].x*g.x + sr2[k].y*g.y + sr2[k].z*g.z + sr2[k].w*g.w;
            accG.w -= sr3[k].x*g.x + sr3[k].y*g.y + sr3[k].z*g.z + sr3[k].w*g.w;
        }
        if (u < GS) {
            const float4* ccol = &sXv[cur][u * 10];
            #pragma unroll
            for (int k = 0; k < 10; ++k) {
                const float4 c = ccol[k];
                accC.x -= sr0[k].x*c.x + sr0[k].y*c.y + sr0[k].z*c.z + sr0[k].w*c.w;
                accC.y -= sr1[k].x*c.x + sr1[k].y*c.y + sr1[k].z*c.z + sr1[k].w*c.w;
                accC.z -= sr2[k].x*c.x + sr2[k].y*c.y + sr2[k].z*c.z + sr2[k].w*c.w;
                accC.w -= sr3[k].x*c.x + sr3[k].y*c.y + sr3[k].z*c.z + sr3[k].w*c.w;
            }
        }
        sGc[nxt][u*11 + pb] = accG;
        if (u < GS) sXv[nxt][u*10 + pb] = accC;
        __syncthreads();
    }
    const int fin = INNER & 1;   // final G / c buffer index (== 1 for odd INNER)

    // ---- outer-loop registers: G rows p, p+20; c values; M row ----
    const int i = t / GS;        // block-row 0..19
    const int p = t % GS;        // component 0..19; partner p+20
    float4 gr0[10], gr1[10];
    {
        const float* Gf = (const float*)sGc[fin];    // G[r][q] at [q*44 + r]
        #pragma unroll
        for (int k = 0; k < 10; ++k) {
            gr0[k].x = Gf[(4*k+0)*44 + p];  gr0[k].y = Gf[(4*k+1)*44 + p];
            gr0[k].z = Gf[(4*k+2)*44 + p];  gr0[k].w = Gf[(4*k+3)*44 + p];
            gr1[k].x = Gf[(4*k+0)*44 + p+20]; gr1[k].y = Gf[(4*k+1)*44 + p+20];
            gr1[k].z = Gf[(4*k+2)*44 + p+20]; gr1[k].w = Gf[(4*k+3)*44 + p+20];
        }
    }
    const float c0 = ((const float*)sXv[fin])[i*PARAM + p];
    const float c1 = ((const float*)sXv[fin])[i*PARAM + p + 20];
    float mrow[GS];
    if (t < 200) {
        const int zi = t / 10;
        #pragma unroll
        for (int j = 0; j < GS; ++j) mrow[j] = sM[zi*GS + j];
    }
    // (reads only — all data final behind the last inner barrier; x0 = c in sXv[fin])

    int cur = fin;
    for (int it = 0; it < OUTER; ++it) {   // ROLLED (see header note)
        // phase 1: Z[zi][cc4] = sum_j M[zi,j] * X[j][cc4]
        if (t < 200) {
            const int zi = t / 10, cc = t - (t/10)*10;
            const float4* X4 = sXv[cur];
            float4 acc = make_float4(0.f, 0.f, 0.f, 0.f);
            #pragma unroll
            for (int j = 0; j < GS; ++j) {
                const float  m = mrow[j];
                const float4 x = X4[j*10 + cc];
                acc.x += m*x.x; acc.y += m*x.y; acc.z += m*x.z; acc.w += m*x.w;
            }
            sZ[t] = acc;
        }
        __syncthreads();
        // phase 2: x'_{i,p} = c - Grow_p · Z_i  (two outputs share Z_i reads)
        const float4* Z4 = &sZ[i*10];
        float a0 = 0.f, a1 = 0.f;
        #pragma unroll
        for (int k = 0; k < 10; ++k) {
            const float4 z = Z4[k];
            a0 += gr0[k].x*z.x + gr0[k].y*z.y + gr0[k].z*z.z + gr0[k].w*z.w;
            a1 += gr1[k].x*z.x + gr1[k].y*z.y + gr1[k].z*z.z + gr1[k].w*z.w;
        }
        const float x0n = c0 - a0, x1n = c1 - a1;
        if (it == OUTER - 1) {
            // epilogue: advrelu(lo=-1,hi=1) == clip
            out[sys*NLOC + i*PARAM + p   ] = fminf(fmaxf(x0n, -1.f), 1.f);
            out[sys*NLOC + i*PARAM + p+20] = fminf(fmaxf(x1n, -1.f), 1.f);
        } else {
            ((float*)sXv[cur ^ 1])[i*PARAM + p   ] = x0n;
            ((float*)sXv[cur ^ 1])[i*PARAM + p+20] = x1n;
            __syncthreads();
            cur ^= 1;
        }
    }
}

extern "C" void kernel_launch(void* const* d_in, const int* in_sizes, int n_in,
                              void* d_out, int out_size, void* d_ws, size_t ws_size,
                              hipStream_t stream) {
    const float* mat = (const float*)d_in[0];  // 8*10*20*20 = 32000
    const float* val = (const float*)d_in[1];  // 8*10*20*40 = 64000
    const float* S   = (const float*)d_in[2];  // 40*40
    const float* Ng  = (const float*)d_in[3];  // 40*40
    float* out = (float*)d_out;                // 64000 f32

    gliam_solve<<<NSYS, NTH, 0, stream>>>(mat, val, S, Ng, out);
}